// Round 3
// baseline (593.314 us; speedup 1.0000x reference)
//
#include <hip/hip_runtime.h>

// ---------------------------------------------------------------------------
// R3: 4-wave blocks, truly register-resident weights.
//  - 256 blocks x 256 threads (4 waves, 1 wave/SIMD, 512-reg budget).
//  - D = A*B, A = W^T fragments, B = activation fragments (LDS rows,
//    stride FS=232 ushorts -> mr*116 words = stride 20 mod 32: 8 consecutive
//    mr hit 8 distinct 4-word bank groups, only free 2-way aliasing).
//  - W1/W2/W3 tiles {w,w+4,w+8} and Wout tiles {w,w+4} live in VGPRs, pinned
//    by opaque inline asm so LLVM cannot rematerialize them from global.
//  - W0 (all 13 tiles) + tile 12 of W1/2/3 served from LDS A-fragments
//    (lane-contiguous 16B reads = conflict-free); wave 3 computes tile 12.
//  - Biases folded as extra K-row with activation 1.0 (bf16) kept resident in
//    LDS rows (feature 101 of sIn, feature 200 of sA/sB).
//  - S, err carried in f32 regs of the lanes owning the Wout C-fragment.
// ---------------------------------------------------------------------------

typedef __attribute__((ext_vector_type(8))) short  bf16x8;
typedef __attribute__((ext_vector_type(4))) float  f32x4;

#define MFMA16(A,B,C) __builtin_amdgcn_mfma_f32_16x16x32_bf16((A),(B),(C),0,0,0)
#define KEEP(x) asm volatile("" : "+v"(x))

#define FS 232                     // activation row stride in ushorts

// packed weight layout (ushort element offsets inside d_ws)
#define OFF1 26624                 // W0: 13 tiles x 4 kit x 512
#define E1   46592                 // W1/2/3: 13 tiles x 7 kit x 512
#define OFF2 (OFF1+E1)
#define OFF3 (OFF2+E1)
#define OFF4 (OFF3+E1)
#define TOTE (OFF4+7*7*512)        // 191488 ushorts

__device__ __forceinline__ unsigned short f2bf(float x){
  unsigned u = __float_as_uint(x);
  return (unsigned short)((u + 0x7fffu + ((u >> 16) & 1u)) >> 16);  // RNE
}

__device__ __forceinline__ unsigned pk2(float a, float b){
#if __has_builtin(__builtin_amdgcn_cvt_pk_bf16_f32)
  typedef __bf16 bf2 __attribute__((ext_vector_type(2)));
  bf2 r = __builtin_amdgcn_cvt_pk_bf16_f32(a, b);
  return __builtin_bit_cast(unsigned, r);
#else
  return (unsigned)f2bf(a) | ((unsigned)f2bf(b) << 16);
#endif
}

// ---------------------------------------------------------------------------
__global__ void pack_w(const float* __restrict__ W0, const float* __restrict__ b0,
                       const float* __restrict__ W1, const float* __restrict__ b1,
                       const float* __restrict__ W2, const float* __restrict__ b2,
                       const float* __restrict__ W3, const float* __restrict__ b3,
                       const float* __restrict__ Wo, const float* __restrict__ bo,
                       unsigned short* __restrict__ out){
  int idx = blockIdx.x * 256 + threadIdx.x;
  if (idx >= TOTE) return;
  const float *Ws, *bs; int KI, NT, local, isw0 = 0;
  if      (idx < OFF1){ Ws = W0; bs = b0; KI = 4; NT = 200; local = idx;        isw0 = 1; }
  else if (idx < OFF2){ Ws = W1; bs = b1; KI = 7; NT = 200; local = idx - OFF1; }
  else if (idx < OFF3){ Ws = W2; bs = b2; KI = 7; NT = 200; local = idx - OFF2; }
  else if (idx < OFF4){ Ws = W3; bs = b3; KI = 7; NT = 200; local = idx - OFF3; }
  else                { Ws = Wo; bs = bo; KI = 7; NT = 100; local = idx - OFF4; }
  int per_tile = KI * 512;
  int tile = local / per_tile;
  int rem  = local - tile * per_tile;
  int kit  = rem >> 9;
  int within = rem & 511;
  int ln = within >> 3, j = within & 7;
  int n = tile * 16 + (ln & 15);          // out-feature
  int k = kit * 32 + (ln >> 4) * 8 + j;   // in-feature (incl. bias row)
  float v = 0.f;
  if (n < NT){
    if (isw0){
      if      (k < 100)  v = Ws[(1 + k) * 200 + n];   // S dims
      else if (k == 100) v = Ws[n];                   // t row
      else if (k == 101) v = bs[n];                   // bias row
    } else {
      if      (k < 200)  v = Ws[k * NT + n];
      else if (k == 200) v = bs[n];                   // bias row
    }
  }
  out[idx] = f2bf(v);
}

// ---------------------------------------------------------------------------
__global__ __launch_bounds__(256, 1) __attribute__((amdgpu_waves_per_eu(1, 1)))
void solver(const float* __restrict__ S0, const float* __restrict__ tg,
            const float* __restrict__ dW, const unsigned short* __restrict__ Wp,
            float* __restrict__ outp)
{
  __shared__ __attribute__((aligned(16))) unsigned short sW0 [26624]; // 53 KB
  __shared__ __attribute__((aligned(16))) unsigned short sT12[10752]; // 21 KB
  __shared__ __attribute__((aligned(16))) unsigned short sIn[16 * FS];
  __shared__ __attribute__((aligned(16))) unsigned short sA [16 * FS];
  __shared__ __attribute__((aligned(16))) unsigned short sB [16 * FS];

  const int tid  = threadIdx.x;
  const int lane = tid & 63;
  const int w    = tid >> 6;          // wave 0..3
  const int q    = lane >> 4;
  const int mr   = lane & 15;         // batch row within block
  const int blk  = blockIdx.x;
  const bool isw3 = (w == 3);
  const int rowoff = mr * FS;
  const int row  = blk * 16 + mr;

  const int f0a = w * 16 + q * 4;            // Wout tile A features (always valid)
  const int f0b = (w + 4) * 16 + q * 4;      // Wout tile B features
  const bool v1ok = (w < 3) && (f0b <= 96);  // tile 6 only q==0

  // ---- init LDS ----
  for (int i = tid; i < 16 * FS / 2; i += 256){
    ((unsigned*)sIn)[i] = 0u; ((unsigned*)sA)[i] = 0u; ((unsigned*)sB)[i] = 0u;
  }
  for (int i = tid; i < 3328; i += 256)            // W0 A-frags (13x4x512)
    ((uint4*)sW0)[i] = ((const uint4*)Wp)[i];
  for (int i = tid; i < 1344; i += 256){           // tile-12 A-frags of W1/2/3
    int L = i / 448;
    ((uint4*)sT12)[i] = *(const uint4*)(Wp + OFF1 + L * E1 + 84 * 512 + (i - L * 448) * 8);
  }
  if (tid < 16){
    sIn[tid * FS + 101] = 0x3F80;                  // bias-activation 1.0
    sA [tid * FS + 200] = 0x3F80;
    sB [tid * FS + 200] = 0x3F80;
  }

  // ---- register-resident weights (pinned) ----
  bf16x8 w1f[3][7], w2f[3][7], w3f[3][7], wo_f[2][7];
#pragma unroll
  for (int j = 0; j < 3; ++j){
    int tl = w + 4 * j;
#pragma unroll
    for (int k = 0; k < 7; ++k){
      w1f[j][k] = *(const bf16x8*)(Wp + OFF1 + (tl * 7 + k) * 512 + lane * 8);
      w2f[j][k] = *(const bf16x8*)(Wp + OFF2 + (tl * 7 + k) * 512 + lane * 8);
      w3f[j][k] = *(const bf16x8*)(Wp + OFF3 + (tl * 7 + k) * 512 + lane * 8);
    }
  }
  {
    int ta = w, tb = (w < 3) ? (w + 4) : w;        // wave3: dup (unused)
#pragma unroll
    for (int k = 0; k < 7; ++k){
      wo_f[0][k] = *(const bf16x8*)(Wp + OFF4 + (ta * 7 + k) * 512 + lane * 8);
      wo_f[1][k] = *(const bf16x8*)(Wp + OFF4 + (tb * 7 + k) * 512 + lane * 8);
    }
  }
#pragma unroll
  for (int j = 0; j < 3; ++j)
#pragma unroll
    for (int k = 0; k < 7; ++k){ KEEP(w1f[j][k]); KEEP(w2f[j][k]); KEEP(w3f[j][k]); }
#pragma unroll
  for (int k = 0; k < 7; ++k){ KEEP(wo_f[0][k]); KEEP(wo_f[1][k]); }

  // ---- state ----
  float Sr0[4], Er0[4] = {0.f,0.f,0.f,0.f};
  float Sr1[4] = {0.f,0.f,0.f,0.f}, Er1[4] = {0.f,0.f,0.f,0.f};
  {
    f32x4 v = *(const f32x4*)(S0 + row * 100 + f0a);
#pragma unroll
    for (int i = 0; i < 4; ++i) Sr0[i] = v[i];
    uint2 pp; pp.x = pk2(Sr0[0], Sr0[1]); pp.y = pk2(Sr0[2], Sr0[3]);
    *(uint2*)&sIn[rowoff + f0a] = pp;
  }
  if (v1ok){
    f32x4 v = *(const f32x4*)(S0 + row * 100 + f0b);
#pragma unroll
    for (int i = 0; i < 4; ++i) Sr1[i] = v[i];
    uint2 pp; pp.x = pk2(Sr1[0], Sr1[1]); pp.y = pk2(Sr1[2], Sr1[3]);
    *(uint2*)&sIn[rowoff + f0b] = pp;
  }

  const float hh = tg[1] - tg[0];
  const float sq = sqrtf(hh);
  float tcur = tg[0];

#define EPI(DST, TL, ACC, T12) {                                              \
    if (!(T12) || q < 2){                                                     \
      int ff = (TL) * 16 + q * 4;                                             \
      float v0 = fmaxf((ACC)[0], 0.f), v1 = fmaxf((ACC)[1], 0.f);             \
      float v2 = fmaxf((ACC)[2], 0.f), v3 = fmaxf((ACC)[3], 0.f);             \
      uint2 pp; pp.x = pk2(v0, v1); pp.y = pk2(v2, v3);                       \
      *(uint2*)&(DST)[rowoff + ff] = pp; } }

#define HIDDEN(SRC, DST, WF, LIDX) {                                          \
    f32x4 c0 = {0.f,0.f,0.f,0.f}, c1 = c0, c2 = c0, c3 = c0;                  \
    _Pragma("unroll")                                                         \
    for (int k = 0; k < 7; ++k){                                              \
      bf16x8 b = *(const bf16x8*)((SRC) + rowoff + k * 32 + q * 8);           \
      c0 = MFMA16(WF[0][k], b, c0);                                           \
      c1 = MFMA16(WF[1][k], b, c1);                                           \
      c2 = MFMA16(WF[2][k], b, c2);                                           \
      if (isw3){                                                              \
        bf16x8 at = *(const bf16x8*)(sT12 + ((LIDX) * 7 + k) * 512 + lane * 8);\
        c3 = MFMA16(at, b, c3); } }                                           \
    EPI(DST, w,     c0, 0)                                                    \
    EPI(DST, w + 4, c1, 0)                                                    \
    EPI(DST, w + 8, c2, 0)                                                    \
    if (isw3) EPI(DST, 12, c3, 1) }

  // ---- time loop ----
  for (int t = 0; t < 100; ++t){
    f32x4 dwf0 = {0.f,0.f,0.f,0.f}, dwf1 = {0.f,0.f,0.f,0.f};
    dwf0 = *(const f32x4*)(dW + row * 10100 + t * 100 + f0a);
    if (v1ok) dwf1 = *(const f32x4*)(dW + row * 10100 + t * 100 + f0b);
    if (tid < 16) sIn[tid * FS + 100] = f2bf(tcur);  // t row
    float tnext = tg[t + 1];
    __syncthreads();                                  // (1) sIn complete

    // ---- L0: W0^T (LDS A-frags) x input ----
    {
      f32x4 c0 = {0.f,0.f,0.f,0.f}, c1 = c0, c2 = c0, c3 = c0;
#pragma unroll
      for (int k = 0; k < 4; ++k){
        bf16x8 b  = *(const bf16x8*)(sIn + rowoff + k * 32 + q * 8);
        bf16x8 a0 = *(const bf16x8*)(sW0 + ((w    ) * 4 + k) * 512 + lane * 8);
        bf16x8 a1 = *(const bf16x8*)(sW0 + ((w + 4) * 4 + k) * 512 + lane * 8);
        bf16x8 a2 = *(const bf16x8*)(sW0 + ((w + 8) * 4 + k) * 512 + lane * 8);
        c0 = MFMA16(a0, b, c0);
        c1 = MFMA16(a1, b, c1);
        c2 = MFMA16(a2, b, c2);
        if (isw3){
          bf16x8 a3 = *(const bf16x8*)(sW0 + (48 + k) * 512 + lane * 8);
          c3 = MFMA16(a3, b, c3);
        }
      }
      EPI(sA, w,     c0, 0)
      EPI(sA, w + 4, c1, 0)
      EPI(sA, w + 8, c2, 0)
      if (isw3) EPI(sA, 12, c3, 1)
    }
    __syncthreads();                                  // (2)
    HIDDEN(sA, sB, w1f, 0)
    __syncthreads();                                  // (3)
    HIDDEN(sB, sA, w2f, 1)
    __syncthreads();                                  // (4)
    HIDDEN(sA, sB, w3f, 2)
    __syncthreads();                                  // (5)

    // ---- L4: Wout^T (regs) x h3; update state; write next S-fragment ----
    {
      f32x4 u0 = {0.f,0.f,0.f,0.f}, u1 = u0;
#pragma unroll
      for (int k = 0; k < 7; ++k){
        bf16x8 b = *(const bf16x8*)(sB + rowoff + k * 32 + q * 8);
        u0 = MFMA16(wo_f[0][k], b, u0);
        if (w < 3) u1 = MFMA16(wo_f[1][k], b, u1);
      }
#pragma unroll
      for (int i = 0; i < 4; ++i){
        float u = u0[i];
        Er0[i] += u * u * hh;
        Sr0[i] += u * (hh + sq * dwf0[i]);
      }
      { uint2 pp; pp.x = pk2(Sr0[0], Sr0[1]); pp.y = pk2(Sr0[2], Sr0[3]);
        *(uint2*)&sIn[rowoff + f0a] = pp; }
      if (v1ok){
#pragma unroll
        for (int i = 0; i < 4; ++i){
          float u = u1[i];
          Er1[i] += u * u * hh;
          Sr1[i] += u * (hh + sq * dwf1[i]);
        }
        uint2 pp; pp.x = pk2(Sr1[0], Sr1[1]); pp.y = pk2(Sr1[2], Sr1[3]);
        *(uint2*)&sIn[rowoff + f0b] = pp;
      }
    }
    tcur = tnext;
  }

  // ---- output: err + S^2 ----
  {
    f32x4 o;
#pragma unroll
    for (int i = 0; i < 4; ++i) o[i] = Er0[i] + Sr0[i] * Sr0[i];
    *(f32x4*)(outp + row * 100 + f0a) = o;
  }
  if (v1ok){
    f32x4 o;
#pragma unroll
    for (int i = 0; i < 4; ++i) o[i] = Er1[i] + Sr1[i] * Sr1[i];
    *(f32x4*)(outp + row * 100 + f0b) = o;
  }
#undef HIDDEN
#undef EPI
}

// ---------------------------------------------------------------------------
extern "C" void kernel_launch(void* const* d_in, const int* in_sizes, int n_in,
                              void* d_out, int out_size, void* d_ws, size_t ws_size,
                              hipStream_t stream) {
  const float* S0 = (const float*)d_in[0];
  const float* tg = (const float*)d_in[1];
  const float* dW = (const float*)d_in[2];
  const float* W0 = (const float*)d_in[3];
  const float* b0 = (const float*)d_in[4];
  const float* W1 = (const float*)d_in[5];
  const float* b1 = (const float*)d_in[6];
  const float* W2 = (const float*)d_in[7];
  const float* b2 = (const float*)d_in[8];
  const float* W3 = (const float*)d_in[9];
  const float* b3 = (const float*)d_in[10];
  const float* Wo = (const float*)d_in[11];
  const float* bo = (const float*)d_in[12];
  unsigned short* Wp = (unsigned short*)d_ws;       // 382976 B used

  pack_w<<<(TOTE + 255) / 256, 256, 0, stream>>>(W0, b0, W1, b1, W2, b2, W3, b3,
                                                 Wo, bo, Wp);
  solver<<<256, 256, 0, stream>>>(S0, tg, dW, Wp, (float*)d_out);
}

// Round 4
// 451.787 us; speedup vs baseline: 1.3133x; 1.3133x over previous
//
#include <hip/hip_runtime.h>

// ---------------------------------------------------------------------------
// R4: R2 structure (256 blocks x 512 thr, 2 waves/SIMD) +
//  - activations in MFMA B-fragment layout [kiter][lane(64)][8] bf16:
//      feature f of batch-row mr lives at ((f>>5)*64 + ((f>>3)&3)*16 + mr)*8
//      + (f&7).  Reads = lane-contiguous ds_read_b128 (conflict-free);
//      epilogue = one aligned ds_write_b64 per tile (even bank spread).
//  -真 register residency: per wave 2 hidden tiles (w, w+8 for w<5) of
//    W1/W2/W3 + 1 Wout tile (w<7) = <=196 VGPRs, KEEP-pinned (budget 256 at
//    2 waves/EU).  W0 (13 tiles) stays in LDS (53 KB).
//  - biases folded as extra K-row vs activation==1.0 (sIn f=101, sA/sB f=200).
//  - S, err carried in f32 regs of the Wout C-fragment owner lanes.
// ---------------------------------------------------------------------------

typedef __attribute__((ext_vector_type(8))) short  bf16x8;
typedef __attribute__((ext_vector_type(4))) float  f32x4;

#define MFMA16(A,B,C) __builtin_amdgcn_mfma_f32_16x16x32_bf16((A),(B),(C),0,0,0)
#define KEEP(x) asm volatile("" : "+v"(x))

// packed weight layout (ushort element offsets inside d_ws)
#define OFF1 26624                 // W0: 13 tiles x 4 kit x 512
#define E1   46592                 // W1/2/3: 13 tiles x 7 kit x 512
#define OFF2 (OFF1+E1)
#define OFF3 (OFF2+E1)
#define OFF4 (OFF3+E1)
#define TOTE (OFF4+7*7*512)        // 191488 ushorts

__device__ __forceinline__ unsigned short f2bf(float x){
  unsigned u = __float_as_uint(x);
  return (unsigned short)((u + 0x7fffu + ((u >> 16) & 1u)) >> 16);  // RNE
}

__device__ __forceinline__ unsigned pk2(float a, float b){
  return (unsigned)f2bf(a) | ((unsigned)f2bf(b) << 16);
}

// ---------------------------------------------------------------------------
__global__ void pack_w(const float* __restrict__ W0, const float* __restrict__ b0,
                       const float* __restrict__ W1, const float* __restrict__ b1,
                       const float* __restrict__ W2, const float* __restrict__ b2,
                       const float* __restrict__ W3, const float* __restrict__ b3,
                       const float* __restrict__ Wo, const float* __restrict__ bo,
                       unsigned short* __restrict__ out){
  int idx = blockIdx.x * 256 + threadIdx.x;
  if (idx >= TOTE) return;
  const float *Ws, *bs; int KI, NT, local, isw0 = 0;
  if      (idx < OFF1){ Ws = W0; bs = b0; KI = 4; NT = 200; local = idx;        isw0 = 1; }
  else if (idx < OFF2){ Ws = W1; bs = b1; KI = 7; NT = 200; local = idx - OFF1; }
  else if (idx < OFF3){ Ws = W2; bs = b2; KI = 7; NT = 200; local = idx - OFF2; }
  else if (idx < OFF4){ Ws = W3; bs = b3; KI = 7; NT = 200; local = idx - OFF3; }
  else                { Ws = Wo; bs = bo; KI = 7; NT = 100; local = idx - OFF4; }
  int per_tile = KI * 512;
  int tile = local / per_tile;
  int rem  = local - tile * per_tile;
  int kit  = rem >> 9;
  int within = rem & 511;
  int ln = within >> 3, j = within & 7;
  int n = tile * 16 + (ln & 15);          // out-feature
  int k = kit * 32 + (ln >> 4) * 8 + j;   // in-feature (incl. bias row)
  float v = 0.f;
  if (n < NT){
    if (isw0){
      if      (k < 100)  v = Ws[(1 + k) * 200 + n];   // S dims
      else if (k == 100) v = Ws[n];                   // t row
      else if (k == 101) v = bs[n];                   // bias row
    } else {
      if      (k < 200)  v = Ws[k * NT + n];
      else if (k == 200) v = bs[n];                   // bias row
    }
  }
  out[idx] = f2bf(v);
}

// ---------------------------------------------------------------------------
__global__ __launch_bounds__(512, 2) __attribute__((amdgpu_waves_per_eu(2, 2)))
void solver(const float* __restrict__ S0, const float* __restrict__ tg,
            const float* __restrict__ dW, const unsigned short* __restrict__ Wp,
            float* __restrict__ outp)
{
  __shared__ __attribute__((aligned(16))) unsigned short sW0[26624]; // 53 KB
  __shared__ __attribute__((aligned(16))) unsigned short sIn[2048];  // [4][64][8]
  __shared__ __attribute__((aligned(16))) unsigned short sA [3584];  // [7][64][8]
  __shared__ __attribute__((aligned(16))) unsigned short sB [3584];

  const int tid  = threadIdx.x;
  const int lane = tid & 63;
  const int w    = tid >> 6;          // wave 0..7
  const int q    = lane >> 4;
  const int mr   = lane & 15;         // batch row within block
  const int row  = blockIdx.x * 16 + mr;
  const bool has2   = (w < 5);        // owns second hidden tile (w+8)
  const bool hasOut = (w < 7);        // owns Wout tile w
  const int f0 = w * 16 + q * 4;      // state feature base (when hasOut)
  const bool fvalid = hasOut && !(w == 6 && q >= 1);   // f0 < 100

  // fragment slot (ushort index) of feature f, row mr
#define FSLOT(f, m) ((((f) >> 5) * 64 + ((((f) >> 3) & 3) * 16) + (m)) * 8 + ((f) & 7))

  // ---- stage W0 + zero activation buffers ----
  for (int i = tid; i < 3328; i += 512)
    ((uint4*)sW0)[i] = ((const uint4*)Wp)[i];
  for (int i = tid; i < 1024; i += 512) ((unsigned*)sIn)[i] = 0u;
  for (int i = tid; i < 1792; i += 512){ ((unsigned*)sA)[i] = 0u; ((unsigned*)sB)[i] = 0u; }
  __syncthreads();                          // zeros visible before slot writes
  if (tid < 16){
    sIn[FSLOT(101, tid)] = 0x3F80;          // bias-activation 1.0
    sA [FSLOT(200, tid)] = 0x3F80;
    sB [FSLOT(200, tid)] = 0x3F80;
  }

  // ---- register-resident weights (pinned; <=196 VGPRs) ----
  const int t1  = has2   ? (w + 8) : w;     // dup for w>=5 (unused)
  const int two = hasOut ? w : 0;
  bf16x8 w1f[2][7], w2f[2][7], w3f[2][7], wo_f[7];
#pragma unroll
  for (int k = 0; k < 7; ++k){
    w1f[0][k] = *(const bf16x8*)(Wp + OFF1 + (w  * 7 + k) * 512 + lane * 8);
    w1f[1][k] = *(const bf16x8*)(Wp + OFF1 + (t1 * 7 + k) * 512 + lane * 8);
    w2f[0][k] = *(const bf16x8*)(Wp + OFF2 + (w  * 7 + k) * 512 + lane * 8);
    w2f[1][k] = *(const bf16x8*)(Wp + OFF2 + (t1 * 7 + k) * 512 + lane * 8);
    w3f[0][k] = *(const bf16x8*)(Wp + OFF3 + (w  * 7 + k) * 512 + lane * 8);
    w3f[1][k] = *(const bf16x8*)(Wp + OFF3 + (t1 * 7 + k) * 512 + lane * 8);
    wo_f[k]   = *(const bf16x8*)(Wp + OFF4 + (two * 7 + k) * 512 + lane * 8);
  }
#pragma unroll
  for (int k = 0; k < 7; ++k){
    KEEP(w1f[0][k]); KEEP(w1f[1][k]);
    KEEP(w2f[0][k]); KEEP(w2f[1][k]);
    KEEP(w3f[0][k]); KEEP(w3f[1][k]);
    KEEP(wo_f[k]);
  }

  // ---- state ----
  float Sr[4] = {0.f,0.f,0.f,0.f}, Er[4] = {0.f,0.f,0.f,0.f};
  if (fvalid){
    f32x4 v = *(const f32x4*)(S0 + row * 100 + f0);
#pragma unroll
    for (int i = 0; i < 4; ++i) Sr[i] = v[i];
    uint2 pp; pp.x = pk2(Sr[0], Sr[1]); pp.y = pk2(Sr[2], Sr[3]);
    *(uint2*)&sIn[FSLOT(f0, mr)] = pp;
  }

  const float hh = tg[1] - tg[0];
  const float sq = sqrtf(hh);
  float tcur = tg[0];

  // epilogue: relu + pack + one b64 write; skip the (tile12,q>=2) slots so the
  // bias-activation at f=200 survives (f>200 pads hit zero weight rows anyway)
#define EPI(DST, TL, ACC) {                                                   \
    if (!((TL) == 12 && q >= 2)){                                             \
      int ff = (TL) * 16 + q * 4;                                             \
      uint2 pp;                                                               \
      pp.x = pk2(fmaxf((ACC)[0], 0.f), fmaxf((ACC)[1], 0.f));                 \
      pp.y = pk2(fmaxf((ACC)[2], 0.f), fmaxf((ACC)[3], 0.f));                 \
      *(uint2*)&(DST)[FSLOT(ff, mr)] = pp; } }

#define HIDDEN(SRC, DST, WF) {                                                \
    f32x4 c0 = {0.f,0.f,0.f,0.f}, c1 = c0;                                    \
    _Pragma("unroll")                                                         \
    for (int k = 0; k < 7; ++k){                                              \
      bf16x8 b = *(const bf16x8*)((SRC) + (k * 64 + lane) * 8);               \
      c0 = MFMA16(WF[0][k], b, c0);                                           \
      if (has2) c1 = MFMA16(WF[1][k], b, c1);                                 \
    }                                                                         \
    EPI(DST, w, c0)                                                           \
    if (has2) EPI(DST, w + 8, c1)                                             \
  }

  // ---- time loop ----
  for (int t = 0; t < 100; ++t){
    f32x4 dwf = {0.f,0.f,0.f,0.f};
    if (fvalid)
      dwf = *(const f32x4*)(dW + row * 10100 + t * 100 + f0);
    if (tid < 16) sIn[FSLOT(100, tid)] = f2bf(tcur);   // t row
    float tnext = tg[t + 1];
    __syncthreads();                                    // (1) sIn complete

    // ---- L0: W0 (LDS A-frags) x input ----
    {
      f32x4 c0 = {0.f,0.f,0.f,0.f}, c1 = c0;
#pragma unroll
      for (int k = 0; k < 4; ++k){
        bf16x8 b  = *(const bf16x8*)(sIn + (k * 64 + lane) * 8);
        bf16x8 a0 = *(const bf16x8*)(sW0 + (w * 4 + k) * 512 + lane * 8);
        c0 = MFMA16(a0, b, c0);
        if (has2){
          bf16x8 a1 = *(const bf16x8*)(sW0 + ((w + 8) * 4 + k) * 512 + lane * 8);
          c1 = MFMA16(a1, b, c1);
        }
      }
      EPI(sA, w, c0)
      if (has2) EPI(sA, w + 8, c1)
    }
    __syncthreads();                                    // (2)
    HIDDEN(sA, sB, w1f)
    __syncthreads();                                    // (3)
    HIDDEN(sB, sA, w2f)
    __syncthreads();                                    // (4)
    HIDDEN(sA, sB, w3f)
    __syncthreads();                                    // (5)

    // ---- L4: Wout (regs) x h3; update state; write next S-fragment ----
    if (hasOut){
      f32x4 u = {0.f,0.f,0.f,0.f};
#pragma unroll
      for (int k = 0; k < 7; ++k){
        bf16x8 b = *(const bf16x8*)(sB + (k * 64 + lane) * 8);
        u = MFMA16(wo_f[k], b, u);
      }
      if (fvalid){
#pragma unroll
        for (int i = 0; i < 4; ++i){
          Er[i] += u[i] * u[i] * hh;
          Sr[i] += u[i] * (hh + sq * dwf[i]);
        }
        uint2 pp; pp.x = pk2(Sr[0], Sr[1]); pp.y = pk2(Sr[2], Sr[3]);
        *(uint2*)&sIn[FSLOT(f0, mr)] = pp;
      }
    }
    tcur = tnext;
  }

  // ---- output: err + S^2 ----
  if (fvalid){
    f32x4 o;
#pragma unroll
    for (int i = 0; i < 4; ++i) o[i] = Er[i] + Sr[i] * Sr[i];
    *(f32x4*)(outp + row * 100 + f0) = o;
  }
#undef HIDDEN
#undef EPI
#undef FSLOT
}

// ---------------------------------------------------------------------------
extern "C" void kernel_launch(void* const* d_in, const int* in_sizes, int n_in,
                              void* d_out, int out_size, void* d_ws, size_t ws_size,
                              hipStream_t stream) {
  const float* S0 = (const float*)d_in[0];
  const float* tg = (const float*)d_in[1];
  const float* dW = (const float*)d_in[2];
  const float* W0 = (const float*)d_in[3];
  const float* b0 = (const float*)d_in[4];
  const float* W1 = (const float*)d_in[5];
  const float* b1 = (const float*)d_in[6];
  const float* W2 = (const float*)d_in[7];
  const float* b2 = (const float*)d_in[8];
  const float* W3 = (const float*)d_in[9];
  const float* b3 = (const float*)d_in[10];
  const float* Wo = (const float*)d_in[11];
  const float* bo = (const float*)d_in[12];
  unsigned short* Wp = (unsigned short*)d_ws;   // 382976 B used

  pack_w<<<(TOTE + 255) / 256, 256, 0, stream>>>(W0, b0, W1, b1, W2, b2, W3, b3,
                                                 Wo, bo, Wp);
  solver<<<256, 512, 0, stream>>>(S0, tg, dW, Wp, (float*)d_out);
}